// Round 3
// baseline (272.591 us; speedup 1.0000x reference)
//
#include <hip/hip_runtime.h>

// Problem constants (from reference): B=64, C=512, H=W=32, N=1, A=16
#define B_DIM 64
#define C_DIM 512
#define A_DIM 16
#define HW    1024           // H*W
#define EPS   1e-5f

// ---------------------------------------------------------------------------
// Kernel 1: per-(b,c) row reduction of x (contiguous 1024 floats each).
// 8 rows per block (4 waves x 2 rows/wave); each lane loads 8 float4s up
// front (128 B in flight); wave shuffle-reduce only. Writes (sum, sumsq)
// as float2 at sums[c*B + b] so kernel 2 reads coalesced float2 per lane.
// ---------------------------------------------------------------------------
__global__ __launch_bounds__(256) void reduce_rows(const float* __restrict__ x,
                                                   float2* __restrict__ sums) {
    const int wave = threadIdx.x >> 6;
    const int lane = threadIdx.x & 63;
    const int rowA = blockIdx.x * 8 + wave * 2;      // row = b*C + c
    const int rowB = rowA + 1;
    const float4* pA = reinterpret_cast<const float4*>(x) + (size_t)rowA * 256;
    const float4* pB = reinterpret_cast<const float4*>(x) + (size_t)rowB * 256;
    const float4 a0 = pA[lane];
    const float4 a1 = pA[lane + 64];
    const float4 a2 = pA[lane + 128];
    const float4 a3 = pA[lane + 192];
    const float4 b0 = pB[lane];
    const float4 b1 = pB[lane + 64];
    const float4 b2 = pB[lane + 128];
    const float4 b3 = pB[lane + 192];

    float sA = (a0.x + a0.y + a0.z + a0.w) + (a1.x + a1.y + a1.z + a1.w)
             + (a2.x + a2.y + a2.z + a2.w) + (a3.x + a3.y + a3.z + a3.w);
    float qA = (a0.x * a0.x + a0.y * a0.y + a0.z * a0.z + a0.w * a0.w)
             + (a1.x * a1.x + a1.y * a1.y + a1.z * a1.z + a1.w * a1.w)
             + (a2.x * a2.x + a2.y * a2.y + a2.z * a2.z + a2.w * a2.w)
             + (a3.x * a3.x + a3.y * a3.y + a3.z * a3.z + a3.w * a3.w);
    float sB = (b0.x + b0.y + b0.z + b0.w) + (b1.x + b1.y + b1.z + b1.w)
             + (b2.x + b2.y + b2.z + b2.w) + (b3.x + b3.y + b3.z + b3.w);
    float qB = (b0.x * b0.x + b0.y * b0.y + b0.z * b0.z + b0.w * b0.w)
             + (b1.x * b1.x + b1.y * b1.y + b1.z * b1.z + b1.w * b1.w)
             + (b2.x * b2.x + b2.y * b2.y + b2.z * b2.z + b2.w * b2.w)
             + (b3.x * b3.x + b3.y * b3.y + b3.z * b3.z + b3.w * b3.w);

#pragma unroll
    for (int off = 32; off > 0; off >>= 1) {
        sA += __shfl_down(sA, off);
        qA += __shfl_down(qA, off);
        sB += __shfl_down(sB, off);
        qB += __shfl_down(qB, off);
    }
    if (lane == 0) {
        int b = rowA >> 9, c = rowA & (C_DIM - 1);
        sums[c * B_DIM + b] = make_float2(sA, qA);
        b = rowB >> 9;  c = rowB & (C_DIM - 1);
        sums[c * B_DIM + b] = make_float2(sB, qB);
    }
}

// ---------------------------------------------------------------------------
// Kernel 2 (fused tail): 64 blocks (one per batch row b) x 256 threads.
// Phase A: each block redundantly computes all 512 channel stats from sums
//          (deterministic -> consistent across blocks), stores its own
//          newx[b][c] row into LDS.
// Phase B: LayerNorm of router weights -> wn_lds[c][a] (32 KB LDS).
// Then: coalesced float4 store of newx row; matmul + softmax from LDS.
// ---------------------------------------------------------------------------
__global__ __launch_bounds__(256) void fused_tail(
    const float2* __restrict__ sums,
    const float* __restrict__ bn_g, const float* __restrict__ bn_b,
    const float* __restrict__ rw, const float* __restrict__ ln_g,
    const float* __restrict__ ln_b, const float* __restrict__ rbias,
    float* __restrict__ newx, float* __restrict__ logits,
    float* __restrict__ probs) {
    __shared__ float x_lds[C_DIM];                  // newx[b][:], 2 KB
    __shared__ float wn_lds[C_DIM * A_DIM];         // wn[c][a], 32 KB
    __shared__ float part[4 * A_DIM];               // cross-wave partials

    const int wave = threadIdx.x >> 6;
    const int lane = threadIdx.x & 63;
    const int b = blockIdx.x;

    // ---- Phase A: channel stats + this block's newx row ----
    for (int k = 0; k < 128; ++k) {
        const int c = wave * 128 + k;
        const float2 t = sums[c * B_DIM + lane];    // lane == batch index
        float ts = t.x, tq = t.y;
#pragma unroll
        for (int off = 32; off > 0; off >>= 1) {
            ts += __shfl_xor(ts, off);
            tq += __shfl_xor(tq, off);
        }
        const float mu  = ts * (1.0f / 65536.0f);   // /(B*H*W)
        const float var = tq * (1.0f / 65536.0f) - mu * mu;
        const float r   = rsqrtf(var + EPS);
        const float s1b = __shfl(t.x, b);           // this block's batch row
        if (lane == 0)
            x_lds[c] = bn_g[c] * (s1b * (1.0f / 1024.0f) - mu) * r + bn_b[c];
    }

    // ---- Phase B: LayerNorm over C of router_weights[:,a] ----
#pragma unroll
    for (int i = 0; i < 4; ++i) {
        const int a = wave * 4 + i;
        float wv[8];
        float s = 0.f, q = 0.f;
#pragma unroll
        for (int j = 0; j < 8; ++j) {
            const int c = j * 64 + lane;
            wv[j] = rw[c * A_DIM + a];
            s += wv[j];
            q += wv[j] * wv[j];
        }
#pragma unroll
        for (int off = 32; off > 0; off >>= 1) {
            s += __shfl_xor(s, off);
            q += __shfl_xor(q, off);
        }
        const float m = s * (1.0f / 512.0f);
        const float v = q * (1.0f / 512.0f) - m * m;
        const float r = rsqrtf(v + EPS);
#pragma unroll
        for (int j = 0; j < 8; ++j) {
            const int c = j * 64 + lane;
            wn_lds[c * A_DIM + a] = (wv[j] - m) * r * ln_g[c] + ln_b[c];
        }
    }
    __syncthreads();

    // ---- coalesced newx row store (threads 0..127, float4 each) ----
    if (threadIdx.x < 128) {
        reinterpret_cast<float4*>(newx + b * C_DIM)[threadIdx.x] =
            reinterpret_cast<const float4*>(x_lds)[threadIdx.x];
    }

    // ---- Phase C: logits + softmax for row b ----
    const int a  = lane & 15;
    const int g  = wave * 4 + (lane >> 4);          // global chunk 0..15
    float acc = 0.f;
#pragma unroll
    for (int j = 0; j < 32; ++j) {
        const int c = g * 32 + j;
        acc += x_lds[c] * wn_lds[c * A_DIM + a];
    }
    acc += __shfl_xor(acc, 16);
    acc += __shfl_xor(acc, 32);
    if (lane < 16) part[wave * A_DIM + a] = acc;
    __syncthreads();
    if (wave == 0 && lane < 16) {
        const float logit = part[a] + part[A_DIM + a] + part[2 * A_DIM + a]
                          + part[3 * A_DIM + a] + rbias[a];
        float mx = logit;
#pragma unroll
        for (int m = 1; m < 16; m <<= 1) mx = fmaxf(mx, __shfl_xor(mx, m));
        const float e = expf(logit - mx);
        float se = e;
#pragma unroll
        for (int m = 1; m < 16; m <<= 1) se += __shfl_xor(se, m);
        logits[b * A_DIM + a] = logit;
        probs[b * A_DIM + a]  = e / se;
    }
}

extern "C" void kernel_launch(void* const* d_in, const int* in_sizes, int n_in,
                              void* d_out, int out_size, void* d_ws, size_t ws_size,
                              hipStream_t stream) {
    const float* x     = (const float*)d_in[0];   // [B,C,H,W]
    const float* rw    = (const float*)d_in[1];   // [1,C,A]
    const float* rbias = (const float*)d_in[2];   // [1,A]
    const float* bn_g  = (const float*)d_in[3];   // [1,C]
    const float* bn_b  = (const float*)d_in[4];
    const float* ln_g  = (const float*)d_in[5];
    const float* ln_b  = (const float*)d_in[6];

    float* out    = (float*)d_out;
    float* newx   = out;                          // 32768 floats: new_x [1,64,512]
    float* logits = out + B_DIM * C_DIM;          // 1024 floats
    float* probs  = logits + B_DIM * A_DIM;       // 1024 floats

    float2* sums = (float2*)d_ws;                 // 32768 float2 [c][b] (sum, sumsq)

    reduce_rows<<<(B_DIM * C_DIM) / 8, 256, 0, stream>>>(x, sums);
    fused_tail<<<B_DIM, 256, 0, stream>>>(sums, bn_g, bn_b, rw, ln_g, ln_b,
                                          rbias, newx, logits, probs);
}

// Round 4
// 206.408 us; speedup vs baseline: 1.3206x; 1.3206x over previous
//
#include <hip/hip_runtime.h>

// Problem constants (from reference): B=64, C=512, H=W=32, N=1, A=16
#define B_DIM 64
#define C_DIM 512
#define A_DIM 16
#define HW    1024           // H*W
#define EPS   1e-5f
#define WN_STRIDE 17         // pad: bank = (17*lane + a) % 32, 17 coprime 32 -> 2-way max

// ---------------------------------------------------------------------------
// Kernel 1: per-(b,c) row reduction of x (contiguous 1024 floats each).
// 8 rows per block (4 waves x 2 rows/wave); each lane loads 8 float4s up
// front (128 B in flight); wave shuffle-reduce only. Writes (sumA, sqA,
// sumB, sqB) as ONE aligned float4 at row-order index rowA/2, i.e. the
// sums array is float2[(b*C + c)] = (sum, sumsq)  ([b][c] layout, so the
// tail kernel's per-step loads are coalesced).
// ---------------------------------------------------------------------------
__global__ __launch_bounds__(256) void reduce_rows(const float* __restrict__ x,
                                                   float4* __restrict__ sums4) {
    const int wave = threadIdx.x >> 6;
    const int lane = threadIdx.x & 63;
    const int rowA = blockIdx.x * 8 + wave * 2;      // row = b*C + c (even)
    const float4* pA = reinterpret_cast<const float4*>(x) + (size_t)rowA * 256;
    const float4* pB = pA + 256;
    const float4 a0 = pA[lane];
    const float4 a1 = pA[lane + 64];
    const float4 a2 = pA[lane + 128];
    const float4 a3 = pA[lane + 192];
    const float4 b0 = pB[lane];
    const float4 b1 = pB[lane + 64];
    const float4 b2 = pB[lane + 128];
    const float4 b3 = pB[lane + 192];

    float sA = (a0.x + a0.y + a0.z + a0.w) + (a1.x + a1.y + a1.z + a1.w)
             + (a2.x + a2.y + a2.z + a2.w) + (a3.x + a3.y + a3.z + a3.w);
    float qA = (a0.x * a0.x + a0.y * a0.y + a0.z * a0.z + a0.w * a0.w)
             + (a1.x * a1.x + a1.y * a1.y + a1.z * a1.z + a1.w * a1.w)
             + (a2.x * a2.x + a2.y * a2.y + a2.z * a2.z + a2.w * a2.w)
             + (a3.x * a3.x + a3.y * a3.y + a3.z * a3.z + a3.w * a3.w);
    float sB = (b0.x + b0.y + b0.z + b0.w) + (b1.x + b1.y + b1.z + b1.w)
             + (b2.x + b2.y + b2.z + b2.w) + (b3.x + b3.y + b3.z + b3.w);
    float qB = (b0.x * b0.x + b0.y * b0.y + b0.z * b0.z + b0.w * b0.w)
             + (b1.x * b1.x + b1.y * b1.y + b1.z * b1.z + b1.w * b1.w)
             + (b2.x * b2.x + b2.y * b2.y + b2.z * b2.z + b2.w * b2.w)
             + (b3.x * b3.x + b3.y * b3.y + b3.z * b3.z + b3.w * b3.w);

#pragma unroll
    for (int off = 32; off > 0; off >>= 1) {
        sA += __shfl_down(sA, off);
        qA += __shfl_down(qA, off);
        sB += __shfl_down(sB, off);
        qB += __shfl_down(qB, off);
    }
    if (lane == 0) {
        sums4[rowA >> 1] = make_float4(sA, qA, sB, qB);
    }
}

// ---------------------------------------------------------------------------
// Kernel 2 (fused tail): 64 blocks (one per batch row b) x 256 threads.
// Phase A (thread-parallel, no shuffles): thread t owns channels t and t+256;
//   accumulates (sum, sumsq) over the 64 batch entries with coalesced float2
//   loads (step j: lanes read 64 consecutive float2 of sums[j*C + ...]).
//   Grabs its own row's s1 when j == b. Computes mu/var/newx -> x_lds.
// Phase B: LayerNorm of router weights -> wn_lds[c*17 + a] (padded stride).
// Then: coalesced float4 newx store; matmul + softmax for row b.
// ---------------------------------------------------------------------------
__global__ __launch_bounds__(256) void fused_tail(
    const float2* __restrict__ sums,
    const float* __restrict__ bn_g, const float* __restrict__ bn_b,
    const float* __restrict__ rw, const float* __restrict__ ln_g,
    const float* __restrict__ ln_b, const float* __restrict__ rbias,
    float* __restrict__ newx, float* __restrict__ logits,
    float* __restrict__ probs) {
    __shared__ float x_lds[C_DIM];                    // newx[b][:], 2 KB
    __shared__ float wn_lds[C_DIM * WN_STRIDE];       // wn[c][a] padded, ~34 KB
    __shared__ float part[4 * A_DIM];                 // cross-wave partials

    const int wave = threadIdx.x >> 6;
    const int lane = threadIdx.x & 63;
    const int b = blockIdx.x;
    const int t = threadIdx.x;

    // ---- Phase A: per-channel batch stats (2 channels per thread) ----
    float s0 = 0.f, q0 = 0.f, s1 = 0.f, q1 = 0.f;
    float s1b0 = 0.f, s1b1 = 0.f;
#pragma unroll 8
    for (int j = 0; j < B_DIM; ++j) {
        const float2 t0 = sums[j * C_DIM + t];
        const float2 t1 = sums[j * C_DIM + t + 256];
        s0 += t0.x; q0 += t0.y;
        s1 += t1.x; q1 += t1.y;
        if (j == b) { s1b0 = t0.x; s1b1 = t1.x; }
    }
    {
        const float mu0  = s0 * (1.0f / 65536.0f);
        const float var0 = q0 * (1.0f / 65536.0f) - mu0 * mu0;
        const float r0   = rsqrtf(var0 + EPS);
        x_lds[t] = bn_g[t] * (s1b0 * (1.0f / 1024.0f) - mu0) * r0 + bn_b[t];
        const float mu1  = s1 * (1.0f / 65536.0f);
        const float var1 = q1 * (1.0f / 65536.0f) - mu1 * mu1;
        const float r1   = rsqrtf(var1 + EPS);
        x_lds[t + 256] = bn_g[t + 256] * (s1b1 * (1.0f / 1024.0f) - mu1) * r1
                       + bn_b[t + 256];
    }

    // ---- Phase B: LayerNorm over C of router_weights[:,a] ----
#pragma unroll
    for (int i = 0; i < 4; ++i) {
        const int a = wave * 4 + i;
        float wv[8];
        float s = 0.f, q = 0.f;
#pragma unroll
        for (int j = 0; j < 8; ++j) {
            const int c = j * 64 + lane;
            wv[j] = rw[c * A_DIM + a];
            s += wv[j];
            q += wv[j] * wv[j];
        }
#pragma unroll
        for (int off = 32; off > 0; off >>= 1) {
            s += __shfl_xor(s, off);
            q += __shfl_xor(q, off);
        }
        const float m = s * (1.0f / 512.0f);
        const float v = q * (1.0f / 512.0f) - m * m;
        const float r = rsqrtf(v + EPS);
#pragma unroll
        for (int j = 0; j < 8; ++j) {
            const int c = j * 64 + lane;
            wn_lds[c * WN_STRIDE + a] = (wv[j] - m) * r * ln_g[c] + ln_b[c];
        }
    }
    __syncthreads();

    // ---- coalesced newx row store (threads 0..127, float4 each) ----
    if (t < 128) {
        reinterpret_cast<float4*>(newx + b * C_DIM)[t] =
            reinterpret_cast<const float4*>(x_lds)[t];
    }

    // ---- Phase C: logits + softmax for row b ----
    const int a = lane & 15;
    const int g = wave * 4 + (lane >> 4);             // global chunk 0..15
    float acc = 0.f;
#pragma unroll
    for (int j = 0; j < 32; ++j) {
        const int c = g * 32 + j;
        acc += x_lds[c] * wn_lds[c * WN_STRIDE + a];
    }
    acc += __shfl_xor(acc, 16);
    acc += __shfl_xor(acc, 32);
    if (lane < 16) part[wave * A_DIM + a] = acc;
    __syncthreads();
    if (wave == 0 && lane < 16) {
        const float logit = part[a] + part[A_DIM + a] + part[2 * A_DIM + a]
                          + part[3 * A_DIM + a] + rbias[a];
        float mx = logit;
#pragma unroll
        for (int m = 1; m < 16; m <<= 1) mx = fmaxf(mx, __shfl_xor(mx, m));
        const float e = expf(logit - mx);
        float se = e;
#pragma unroll
        for (int m = 1; m < 16; m <<= 1) se += __shfl_xor(se, m);
        logits[b * A_DIM + a] = logit;
        probs[b * A_DIM + a]  = e / se;
    }
}

extern "C" void kernel_launch(void* const* d_in, const int* in_sizes, int n_in,
                              void* d_out, int out_size, void* d_ws, size_t ws_size,
                              hipStream_t stream) {
    const float* x     = (const float*)d_in[0];   // [B,C,H,W]
    const float* rw    = (const float*)d_in[1];   // [1,C,A]
    const float* rbias = (const float*)d_in[2];   // [1,A]
    const float* bn_g  = (const float*)d_in[3];   // [1,C]
    const float* bn_b  = (const float*)d_in[4];
    const float* ln_g  = (const float*)d_in[5];
    const float* ln_b  = (const float*)d_in[6];

    float* out    = (float*)d_out;
    float* newx   = out;                          // 32768 floats: new_x [1,64,512]
    float* logits = out + B_DIM * C_DIM;          // 1024 floats
    float* probs  = logits + B_DIM * A_DIM;       // 1024 floats

    float4* sums4 = (float4*)d_ws;                // float2[b*C+c] = (sum, sumsq)
    const float2* sums = (const float2*)d_ws;

    reduce_rows<<<(B_DIM * C_DIM) / 8, 256, 0, stream>>>(x, sums4);
    fused_tail<<<B_DIM, 256, 0, stream>>>(sums, bn_g, bn_b, rw, ln_g, ln_b,
                                          rbias, newx, logits, probs);
}